// Round 4
// baseline (633.790 us; speedup 1.0000x reference)
//
#include <hip/hip_runtime.h>
#include <hip/hip_bf16.h>
#include <cstdint>

typedef __hip_bfloat16 bf16;
typedef __attribute__((ext_vector_type(4))) float f32x4;
typedef __attribute__((ext_vector_type(8))) __bf16 bf16x8;

#define SCALE 0.17677669529663687f

// ---- workspace offsets (bytes) ----
#define OFF_WTQ   0
#define OFF_WTP   221184
#define OFF_WT1   294912
#define OFF_WT2   589824
#define OFF_RMAP  884736
#define OFF_A     1286144
#define OFF_B     39821312
#define OFF_C     193961984

__global__ __launch_bounds__(256) void prep_k(
    const float* __restrict__ qkv_w, const float* __restrict__ proj_w,
    const float* __restrict__ w1, const float* __restrict__ w2,
    bf16* __restrict__ wtq, bf16* __restrict__ wtp,
    bf16* __restrict__ wt1, bf16* __restrict__ wt2, int* __restrict__ rmap)
{
  int i = blockIdx.x * 256 + threadIdx.x;
  if (i < 110592) {                       // qkv_w (192,576) -> wtq[n][k]
    int n = i / 192, k = i - n * 192;
    wtq[i] = __float2bfloat16(qkv_w[k * 576 + n]);
  } else if (i < 147456) {                // proj_w (192,192)
    int j = i - 110592; int n = j / 192, k = j - n * 192;
    wtp[j] = __float2bfloat16(proj_w[k * 192 + n]);
  } else if (i < 294912) {                // w1 (192,768) -> wt1[768][192]
    int j = i - 147456; int n = j / 192, k = j - n * 192;
    wt1[j] = __float2bfloat16(w1[k * 768 + n]);
  } else if (i < 442368) {                // w2 (768,192) -> wt2[192][768]
    int j = i - 294912; int n = j / 768, k = j - n * 768;
    wt2[j] = __float2bfloat16(w2[k * 192 + n]);
  } else if (i < 542720) {                // rowmap: window row -> natural row
    int m = i - 442368;
    int win = m / 49, nn = m - win * 49;
    int b = win >> 6, iw = win & 63;
    int wh = iw >> 3, ww = iw & 7;
    int ty = nn / 7, tx = nn - ty * 7;
    int rr = wh * 7 + ty + 3; if (rr >= 56) rr -= 56;
    int cc = ww * 7 + tx + 3; if (cc >= 56) cc -= 56;
    rmap[m] = b * 3136 + rr * 56 + cc;
  }
}

// LayerNorm over 192, one wave per row, gather permutation, bf16 out
template<bool MAP>
__global__ __launch_bounds__(256) void ln_k(
    const float* __restrict__ x, const float* __restrict__ g,
    const float* __restrict__ b, const int* __restrict__ rmap,
    bf16* __restrict__ out)
{
  int wv = threadIdx.x >> 6, lane = threadIdx.x & 63;
  long m = (long)blockIdx.x * 4 + wv;
  long src = MAP ? (long)rmap[m] : m;
  const float* row = x + src * 192;
  float v0 = row[lane], v1 = row[lane + 64], v2 = row[lane + 128];
  float s = v0 + v1 + v2;
  #pragma unroll
  for (int d = 1; d < 64; d <<= 1) s += __shfl_xor(s, d, 64);
  float mu = s * (1.0f / 192.0f);
  float d0 = v0 - mu, d1 = v1 - mu, d2 = v2 - mu;
  float q = d0 * d0 + d1 * d1 + d2 * d2;
  #pragma unroll
  for (int d = 1; d < 64; d <<= 1) q += __shfl_xor(q, d, 64);
  float inv = 1.0f / sqrtf(q * (1.0f / 192.0f) + 1e-5f);
  bf16* o = out + m * 192;
  o[lane]       = __float2bfloat16(d0 * inv * g[lane]       + b[lane]);
  o[lane + 64]  = __float2bfloat16(d1 * inv * g[lane + 64]  + b[lane + 64]);
  o[lane + 128] = __float2bfloat16(d2 * inv * g[lane + 128] + b[lane + 128]);
}

// GEMM (single-buffered, R1 version): C = A @ Wt^T + bias, fused epilogue.
// MODE 0: ->bf16 qkv   1: +x residual scatter ->f32 h
template<int MODE, int KD>
__global__ __launch_bounds__(256) void gemm_k(
    const bf16* __restrict__ A, const bf16* __restrict__ Bt,
    const float* __restrict__ bias, const float* __restrict__ extra,
    const int* __restrict__ rmap, void* __restrict__ outp)
{
  __shared__ bf16 As[128 * 64];
  const int tid = threadIdx.x;
  const int lane = tid & 63;
  const int w = tid >> 6;
  const int wm = w >> 1, wn = w & 1;
  const long m0 = (long)blockIdx.y * 128;
  const int n0 = blockIdx.x * 64;
  const int r = lane & 15, kb = lane >> 4;

  f32x4 acc[4][2];
  #pragma unroll
  for (int a = 0; a < 4; ++a)
    #pragma unroll
    for (int bb = 0; bb < 2; ++bb) acc[a][bb] = (f32x4){0.f, 0.f, 0.f, 0.f};

  for (int k0 = 0; k0 < KD; k0 += 64) {
    #pragma unroll
    for (int it = 0; it < 4; ++it) {
      int li = tid + it * 256;
      int m = li >> 3;
      int sl = (li & 7) ^ (m & 7);
      const bf16* src = A + (m0 + m) * KD + k0 + sl * 8;
      bf16* dst = As + (size_t)(w * 64 + it * 256) * 8;
      __builtin_amdgcn_global_load_lds(
          (const __attribute__((address_space(1))) unsigned int*)src,
          (__attribute__((address_space(3))) unsigned int*)dst, 16, 0, 0);
    }
    __syncthreads();

    bf16x8 af[2][4], bfr[2][2];
    #pragma unroll
    for (int h2 = 0; h2 < 2; ++h2) {
      #pragma unroll
      for (int mi = 0; mi < 4; ++mi) {
        int m = wm * 64 + mi * 16 + r;
        int slot = (h2 * 4 + kb) ^ (r & 7);
        af[h2][mi] = *(const bf16x8*)(As + m * 64 + slot * 8);
      }
      #pragma unroll
      for (int ni = 0; ni < 2; ++ni) {
        int n = n0 + wn * 32 + ni * 16 + r;
        bfr[h2][ni] = *(const bf16x8*)(Bt + (long)n * KD + k0 + h2 * 32 + kb * 8);
      }
    }
    #pragma unroll
    for (int h2 = 0; h2 < 2; ++h2)
      #pragma unroll
      for (int mi = 0; mi < 4; ++mi)
        #pragma unroll
        for (int ni = 0; ni < 2; ++ni)
          acc[mi][ni] = __builtin_amdgcn_mfma_f32_16x16x32_bf16(
              af[h2][mi], bfr[h2][ni], acc[mi][ni], 0, 0, 0);
    __syncthreads();
  }

  #pragma unroll
  for (int mi = 0; mi < 4; ++mi) {
    #pragma unroll
    for (int ni = 0; ni < 2; ++ni) {
      int col = n0 + wn * 32 + ni * 16 + r;
      float bb = bias[col];
      #pragma unroll
      for (int rr = 0; rr < 4; ++rr) {
        long row = m0 + wm * 64 + mi * 16 + kb * 4 + rr;
        float c = acc[mi][ni][rr] + bb;
        if constexpr (MODE == 0) {
          ((bf16*)outp)[row * 576 + col] = __float2bfloat16(c);
        } else {
          long gr = rmap[row];
          ((float*)outp)[gr * 192 + col] = extra[gr * 192 + col] + c;
        }
      }
    }
  }
}

// ---------------- Fused MLP ----------------
// out = h + gelu(LN2(h) @ w1 + b1) @ w2 + b2
// Block: 64 rows, 256 threads (4 waves, 2x2). Hidden in 4 chunks of 192,
// chunk lives only in LDS. LPAD=196 breaks stride-192 bank conflicts.
#define LPAD 196
__global__ __launch_bounds__(256) void mlp_k(
    const float* __restrict__ h, const float* __restrict__ g2,
    const float* __restrict__ bg2, const bf16* __restrict__ w1t,
    const float* __restrict__ b1, const bf16* __restrict__ w2t,
    const float* __restrict__ b2, float* __restrict__ outp)
{
  __shared__ bf16 Al[64 * LPAD];
  __shared__ bf16 Hl[64 * LPAD];
  const int tid = threadIdx.x;
  const int lane = tid & 63, w = tid >> 6;
  const int wm = w >> 1, wn = w & 1;
  const int r = lane & 15, kb = lane >> 4;
  const long m0 = (long)blockIdx.x * 64;

  // --- LN2: each wave handles 16 rows ---
  {
    float gv0 = g2[lane], gv1 = g2[lane + 64], gv2 = g2[lane + 128];
    float bv0 = bg2[lane], bv1 = bg2[lane + 64], bv2 = bg2[lane + 128];
    #pragma unroll
    for (int half = 0; half < 2; ++half) {
      float va[8][3];
      #pragma unroll
      for (int i = 0; i < 8; ++i) {
        const float* row = h + (m0 + w * 16 + half * 8 + i) * 192;
        va[i][0] = row[lane]; va[i][1] = row[lane + 64]; va[i][2] = row[lane + 128];
      }
      #pragma unroll
      for (int i = 0; i < 8; ++i) {
        float s = va[i][0] + va[i][1] + va[i][2];
        #pragma unroll
        for (int d = 1; d < 64; d <<= 1) s += __shfl_xor(s, d, 64);
        float mu = s * (1.0f / 192.0f);
        float d0 = va[i][0] - mu, d1 = va[i][1] - mu, d2 = va[i][2] - mu;
        float q = d0 * d0 + d1 * d1 + d2 * d2;
        #pragma unroll
        for (int d = 1; d < 64; d <<= 1) q += __shfl_xor(q, d, 64);
        float inv = 1.0f / sqrtf(q * (1.0f / 192.0f) + 1e-5f);
        bf16* o = Al + (w * 16 + half * 8 + i) * LPAD;
        o[lane]       = __float2bfloat16(d0 * inv * gv0 + bv0);
        o[lane + 64]  = __float2bfloat16(d1 * inv * gv1 + bv1);
        o[lane + 128] = __float2bfloat16(d2 * inv * gv2 + bv2);
      }
    }
  }
  __syncthreads();

  f32x4 oacc[2][6];
  #pragma unroll
  for (int mi = 0; mi < 2; ++mi)
    #pragma unroll
    for (int nj = 0; nj < 6; ++nj) oacc[mi][nj] = (f32x4){0.f, 0.f, 0.f, 0.f};

  for (int c = 0; c < 4; ++c) {
    // hidden chunk: Hc = gelu(Al @ w1t[c*192..+192][:] + b1c), 64x192
    f32x4 hacc[2][6];
    #pragma unroll
    for (int mi = 0; mi < 2; ++mi)
      #pragma unroll
      for (int nj = 0; nj < 6; ++nj) hacc[mi][nj] = (f32x4){0.f, 0.f, 0.f, 0.f};

    #pragma unroll
    for (int ks = 0; ks < 6; ++ks) {
      bf16x8 af[2], bfr[6];
      #pragma unroll
      for (int mi = 0; mi < 2; ++mi)
        af[mi] = *(const bf16x8*)(Al + (wm * 32 + mi * 16 + r) * LPAD + ks * 32 + kb * 8);
      #pragma unroll
      for (int nj = 0; nj < 6; ++nj)
        bfr[nj] = *(const bf16x8*)(w1t + (c * 192 + wn * 96 + nj * 16 + r) * 192 + ks * 32 + kb * 8);
      #pragma unroll
      for (int mi = 0; mi < 2; ++mi)
        #pragma unroll
        for (int nj = 0; nj < 6; ++nj)
          hacc[mi][nj] = __builtin_amdgcn_mfma_f32_16x16x32_bf16(af[mi], bfr[nj], hacc[mi][nj], 0, 0, 0);
    }
    // gelu -> Hl   (x*sigmoid(1.5957692x + 0.0713548x^3), |err|<~1e-3)
    #pragma unroll
    for (int nj = 0; nj < 6; ++nj) {
      float b1v = b1[c * 192 + wn * 96 + nj * 16 + r];
      #pragma unroll
      for (int mi = 0; mi < 2; ++mi) {
        #pragma unroll
        for (int rr = 0; rr < 4; ++rr) {
          float xv = hacc[mi][nj][rr] + b1v;
          float t = __expf(fmaf(0.0713548162f * xv, xv * xv, 1.5957692f * xv));
          float ge = xv * t / (t + 1.0f);
          Hl[(wm * 32 + mi * 16 + kb * 4 + rr) * LPAD + wn * 96 + nj * 16 + r] = __float2bfloat16(ge);
        }
      }
    }
    __syncthreads();   // Hl chunk complete before fc2 reads

    // fc2 partial: oacc += Hc @ w2t[:, c*192..+192]
    #pragma unroll
    for (int ks = 0; ks < 6; ++ks) {
      bf16x8 af2[2], bf2[6];
      #pragma unroll
      for (int mi = 0; mi < 2; ++mi)
        af2[mi] = *(const bf16x8*)(Hl + (wm * 32 + mi * 16 + r) * LPAD + ks * 32 + kb * 8);
      #pragma unroll
      for (int nj = 0; nj < 6; ++nj)
        bf2[nj] = *(const bf16x8*)(w2t + (wn * 96 + nj * 16 + r) * 768 + c * 192 + ks * 32 + kb * 8);
      #pragma unroll
      for (int mi = 0; mi < 2; ++mi)
        #pragma unroll
        for (int nj = 0; nj < 6; ++nj)
          oacc[mi][nj] = __builtin_amdgcn_mfma_f32_16x16x32_bf16(af2[mi], bf2[nj], oacc[mi][nj], 0, 0, 0);
    }
    __syncthreads();   // fc2 reads done before next chunk overwrites Hl
  }

  // epilogue: out = h + oacc + b2
  #pragma unroll
  for (int mi = 0; mi < 2; ++mi) {
    #pragma unroll
    for (int nj = 0; nj < 6; ++nj) {
      int col = wn * 96 + nj * 16 + r;
      float b2v = b2[col];
      #pragma unroll
      for (int rr = 0; rr < 4; ++rr) {
        long row = m0 + wm * 32 + mi * 16 + kb * 4 + rr;
        outp[row * 192 + col] = h[row * 192 + col] + oacc[mi][nj][rr] + b2v;
      }
    }
  }
}

// Attention: one wave per (window, head). 49 tokens padded to 64.
__global__ __launch_bounds__(64) void attn_k(
    const bf16* __restrict__ qkv, const float* __restrict__ rpb,
    bf16* __restrict__ aout)
{
  __shared__ bf16 P[64 * 72];
  __shared__ bf16 Vt[32 * 72];
  int lane = threadIdx.x;
  int r = lane & 15, kb = lane >> 4;
  int head = blockIdx.x % 6;
  int win = blockIdx.x / 6;
  int iw = win & 63;
  int wh = iw >> 3, ww = iw & 7;
  const bf16* base = qkv + (long)win * (49 * 576);

  bf16x8 qf[4], kf[4];
  #pragma unroll
  for (int t = 0; t < 4; ++t) {
    int row = t * 16 + r;
    if (row < 49) {
      qf[t] = *(const bf16x8*)(base + row * 576 + head * 32 + kb * 8);
      kf[t] = *(const bf16x8*)(base + row * 576 + 192 + head * 32 + kb * 8);
    } else {
      qf[t] = (bf16x8){0, 0, 0, 0, 0, 0, 0, 0};
      kf[t] = (bf16x8){0, 0, 0, 0, 0, 0, 0, 0};
    }
  }
  f32x4 zero = {0.f, 0.f, 0.f, 0.f};
  f32x4 s[4][4];
  #pragma unroll
  for (int ti = 0; ti < 4; ++ti)
    #pragma unroll
    for (int tj = 0; tj < 4; ++tj)
      s[ti][tj] = __builtin_amdgcn_mfma_f32_16x16x32_bf16(qf[ti], kf[tj], zero, 0, 0, 0);

  {
    int j = lane;
    if (j < 49) {
      #pragma unroll
      for (int d0 = 0; d0 < 32; d0 += 8) {
        bf16x8 v8 = *(const bf16x8*)(base + j * 576 + 384 + head * 32 + d0);
        #pragma unroll
        for (int u = 0; u < 8; ++u) Vt[(d0 + u) * 72 + j] = *((const bf16*)&v8 + u);
      }
    } else {
      for (int d = 0; d < 32; ++d) Vt[d * 72 + j] = __float2bfloat16(0.0f);
    }
  }

  #pragma unroll
  for (int ti = 0; ti < 4; ++ti) {
    #pragma unroll
    for (int rr = 0; rr < 4; ++rr) {
      int i = ti * 16 + kb * 4 + rr;
      int ii = i < 49 ? i : 48;
      int yi = ii / 7, xi = ii - yi * 7;
      int ari = wh * 7 + yi, aci = ww * 7 + xi;
      int gi = (ari < 49 ? 0 : (ari < 53 ? 1 : 2)) * 3 + (aci < 49 ? 0 : (aci < 53 ? 1 : 2));
      float vals[4];
      #pragma unroll
      for (int tj = 0; tj < 4; ++tj) {
        int j = tj * 16 + r;
        int jj = j < 49 ? j : 48;
        int yj = jj / 7, xj = jj - yj * 7;
        float pb = rpb[((yi - yj + 6) * 13 + (xi - xj + 6)) * 6 + head];
        int arj = wh * 7 + yj, acj = ww * 7 + xj;
        int gj = (arj < 49 ? 0 : (arj < 53 ? 1 : 2)) * 3 + (acj < 49 ? 0 : (acj < 53 ? 1 : 2));
        float v = s[ti][tj][rr] * SCALE + pb;
        if (gi != gj) v -= 100.0f;
        if (i >= 49 || j >= 49) v = -1e30f;
        vals[tj] = v;
      }
      float mx = fmaxf(fmaxf(vals[0], vals[1]), fmaxf(vals[2], vals[3]));
      #pragma unroll
      for (int d = 1; d < 16; d <<= 1) mx = fmaxf(mx, __shfl_xor(mx, d, 64));
      float e0 = __expf(vals[0] - mx), e1 = __expf(vals[1] - mx);
      float e2 = __expf(vals[2] - mx), e3 = __expf(vals[3] - mx);
      float sum = e0 + e1 + e2 + e3;
      #pragma unroll
      for (int d = 1; d < 16; d <<= 1) sum += __shfl_xor(sum, d, 64);
      float inv = 1.0f / sum;
      P[i * 72 + 0  + r] = __float2bfloat16(e0 * inv);
      P[i * 72 + 16 + r] = __float2bfloat16(e1 * inv);
      P[i * 72 + 32 + r] = __float2bfloat16(e2 * inv);
      P[i * 72 + 48 + r] = __float2bfloat16(e3 * inv);
    }
  }
  __syncthreads();

  f32x4 o[4][2];
  #pragma unroll
  for (int ti = 0; ti < 4; ++ti)
    #pragma unroll
    for (int dt = 0; dt < 2; ++dt) o[ti][dt] = zero;
  #pragma unroll
  for (int kt = 0; kt < 2; ++kt) {
    bf16x8 pf[4], vf[2];
    #pragma unroll
    for (int ti = 0; ti < 4; ++ti)
      pf[ti] = *(const bf16x8*)(P + (ti * 16 + r) * 72 + kt * 32 + kb * 8);
    #pragma unroll
    for (int dt = 0; dt < 2; ++dt)
      vf[dt] = *(const bf16x8*)(Vt + (dt * 16 + r) * 72 + kt * 32 + kb * 8);
    #pragma unroll
    for (int ti = 0; ti < 4; ++ti)
      #pragma unroll
      for (int dt = 0; dt < 2; ++dt)
        o[ti][dt] = __builtin_amdgcn_mfma_f32_16x16x32_bf16(pf[ti], vf[dt], o[ti][dt], 0, 0, 0);
  }
  #pragma unroll
  for (int ti = 0; ti < 4; ++ti)
    #pragma unroll
    for (int dt = 0; dt < 2; ++dt)
      #pragma unroll
      for (int rr = 0; rr < 4; ++rr) {
        int i = ti * 16 + kb * 4 + rr;
        if (i < 49)
          aout[((long)win * 49 + i) * 192 + head * 32 + dt * 16 + r] =
              __float2bfloat16(o[ti][dt][rr]);
      }
}

extern "C" void kernel_launch(void* const* d_in, const int* in_sizes, int n_in,
                              void* d_out, int out_size, void* d_ws, size_t ws_size,
                              hipStream_t stream)
{
  const float* x      = (const float*)d_in[0];
  const float* qkv_w  = (const float*)d_in[1];
  const float* qkv_b  = (const float*)d_in[2];
  const float* proj_w = (const float*)d_in[3];
  const float* proj_b = (const float*)d_in[4];
  const float* rpb    = (const float*)d_in[5];
  const float* ln1_g  = (const float*)d_in[6];
  const float* ln1_b  = (const float*)d_in[7];
  const float* ln2_g  = (const float*)d_in[8];
  const float* ln2_b  = (const float*)d_in[9];
  const float* w1     = (const float*)d_in[10];
  const float* b1     = (const float*)d_in[11];
  const float* w2     = (const float*)d_in[12];
  const float* b2     = (const float*)d_in[13];

  char* ws = (char*)d_ws;
  bf16* wtq = (bf16*)(ws + OFF_WTQ);
  bf16* wtp = (bf16*)(ws + OFF_WTP);
  bf16* wt1 = (bf16*)(ws + OFF_WT1);
  bf16* wt2 = (bf16*)(ws + OFF_WT2);
  int*  rmap = (int*)(ws + OFF_RMAP);
  bf16* Abuf = (bf16*)(ws + OFF_A);
  bf16* Bbuf = (bf16*)(ws + OFF_B);
  float* hbuf = (float*)(ws + OFF_C);

  prep_k<<<2120, 256, 0, stream>>>(qkv_w, proj_w, w1, w2, wtq, wtp, wt1, wt2, rmap);
  ln_k<true><<<25088, 256, 0, stream>>>(x, ln1_g, ln1_b, rmap, Abuf);
  gemm_k<0, 192><<<dim3(9, 784), 256, 0, stream>>>(Abuf, wtq, qkv_b, nullptr, nullptr, Bbuf);
  attn_k<<<12288, 64, 0, stream>>>(Bbuf, rpb, Abuf);
  gemm_k<1, 192><<<dim3(3, 784), 256, 0, stream>>>(Abuf, wtp, proj_b, x, rmap, hbuf);
  mlp_k<<<1568, 256, 0, stream>>>(hbuf, ln2_g, ln2_b, wt1, b1, wt2, b2, (float*)d_out);
}

// Round 6
// 526.966 us; speedup vs baseline: 1.2027x; 1.2027x over previous
//
#include <hip/hip_runtime.h>
#include <hip/hip_bf16.h>
#include <cstdint>

typedef __hip_bfloat16 bf16;
typedef __attribute__((ext_vector_type(4))) float f32x4;
typedef __attribute__((ext_vector_type(8))) __bf16 bf16x8;

#define SCALE 0.17677669529663687f

// ---- workspace offsets (bytes) ----
#define OFF_WTQ   0
#define OFF_WTP   221184
#define OFF_WT1   294912
#define OFF_WT2   589824
#define OFF_RMAP  884736
#define OFF_A     1286144
#define OFF_B     39821312
#define OFF_C     193961984

__global__ __launch_bounds__(256) void prep_k(
    const float* __restrict__ qkv_w, const float* __restrict__ proj_w,
    const float* __restrict__ w1, const float* __restrict__ w2,
    bf16* __restrict__ wtq, bf16* __restrict__ wtp,
    bf16* __restrict__ wt1, bf16* __restrict__ wt2, int* __restrict__ rmap)
{
  int i = blockIdx.x * 256 + threadIdx.x;
  if (i < 110592) {                       // qkv_w (192,576) -> wtq[n][k]
    int n = i / 192, k = i - n * 192;
    wtq[i] = __float2bfloat16(qkv_w[k * 576 + n]);
  } else if (i < 147456) {                // proj_w (192,192)
    int j = i - 110592; int n = j / 192, k = j - n * 192;
    wtp[j] = __float2bfloat16(proj_w[k * 192 + n]);
  } else if (i < 294912) {                // w1 (192,768) -> wt1[768][192]
    int j = i - 147456; int n = j / 192, k = j - n * 192;
    wt1[j] = __float2bfloat16(w1[k * 768 + n]);
  } else if (i < 442368) {                // w2 (768,192) -> wt2[192][768]
    int j = i - 294912; int n = j / 768, k = j - n * 768;
    wt2[j] = __float2bfloat16(w2[k * 192 + n]);
  } else if (i < 542720) {                // rowmap: window row -> natural row
    int m = i - 442368;
    int win = m / 49, nn = m - win * 49;
    int b = win >> 6, iw = win & 63;
    int wh = iw >> 3, ww = iw & 7;
    int ty = nn / 7, tx = nn - ty * 7;
    int rr = wh * 7 + ty + 3; if (rr >= 56) rr -= 56;
    int cc = ww * 7 + tx + 3; if (cc >= 56) cc -= 56;
    rmap[m] = b * 3136 + rr * 56 + cc;
  }
}

// LayerNorm over 192, one wave per row, gather permutation, bf16 out
template<bool MAP>
__global__ __launch_bounds__(256) void ln_k(
    const float* __restrict__ x, const float* __restrict__ g,
    const float* __restrict__ b, const int* __restrict__ rmap,
    bf16* __restrict__ out)
{
  int wv = threadIdx.x >> 6, lane = threadIdx.x & 63;
  long m = (long)blockIdx.x * 4 + wv;
  long src = MAP ? (long)rmap[m] : m;
  const float* row = x + src * 192;
  float v0 = row[lane], v1 = row[lane + 64], v2 = row[lane + 128];
  float s = v0 + v1 + v2;
  #pragma unroll
  for (int d = 1; d < 64; d <<= 1) s += __shfl_xor(s, d, 64);
  float mu = s * (1.0f / 192.0f);
  float d0 = v0 - mu, d1 = v1 - mu, d2 = v2 - mu;
  float q = d0 * d0 + d1 * d1 + d2 * d2;
  #pragma unroll
  for (int d = 1; d < 64; d <<= 1) q += __shfl_xor(q, d, 64);
  float inv = 1.0f / sqrtf(q * (1.0f / 192.0f) + 1e-5f);
  bf16* o = out + m * 192;
  o[lane]       = __float2bfloat16(d0 * inv * g[lane]       + b[lane]);
  o[lane + 64]  = __float2bfloat16(d1 * inv * g[lane + 64]  + b[lane + 64]);
  o[lane + 128] = __float2bfloat16(d2 * inv * g[lane + 128] + b[lane + 128]);
}

// GEMM (single-buffered): C = A @ Wt^T + bias, fused epilogue.
// MODE 0: ->bf16 qkv   1: +x residual scatter ->f32 h
template<int MODE, int KD>
__global__ __launch_bounds__(256) void gemm_k(
    const bf16* __restrict__ A, const bf16* __restrict__ Bt,
    const float* __restrict__ bias, const float* __restrict__ extra,
    const int* __restrict__ rmap, void* __restrict__ outp)
{
  __shared__ bf16 As[128 * 64];
  const int tid = threadIdx.x;
  const int lane = tid & 63;
  const int w = tid >> 6;
  const int wm = w >> 1, wn = w & 1;
  const long m0 = (long)blockIdx.y * 128;
  const int n0 = blockIdx.x * 64;
  const int r = lane & 15, kb = lane >> 4;

  f32x4 acc[4][2];
  #pragma unroll
  for (int a = 0; a < 4; ++a)
    #pragma unroll
    for (int bb = 0; bb < 2; ++bb) acc[a][bb] = (f32x4){0.f, 0.f, 0.f, 0.f};

  for (int k0 = 0; k0 < KD; k0 += 64) {
    #pragma unroll
    for (int it = 0; it < 4; ++it) {
      int li = tid + it * 256;
      int m = li >> 3;
      int sl = (li & 7) ^ (m & 7);
      const bf16* src = A + (m0 + m) * KD + k0 + sl * 8;
      bf16* dst = As + (size_t)(w * 64 + it * 256) * 8;
      __builtin_amdgcn_global_load_lds(
          (const __attribute__((address_space(1))) unsigned int*)src,
          (__attribute__((address_space(3))) unsigned int*)dst, 16, 0, 0);
    }
    __syncthreads();

    bf16x8 af[2][4], bfr[2][2];
    #pragma unroll
    for (int h2 = 0; h2 < 2; ++h2) {
      #pragma unroll
      for (int mi = 0; mi < 4; ++mi) {
        int m = wm * 64 + mi * 16 + r;
        int slot = (h2 * 4 + kb) ^ (r & 7);
        af[h2][mi] = *(const bf16x8*)(As + m * 64 + slot * 8);
      }
      #pragma unroll
      for (int ni = 0; ni < 2; ++ni) {
        int n = n0 + wn * 32 + ni * 16 + r;
        bfr[h2][ni] = *(const bf16x8*)(Bt + (long)n * KD + k0 + h2 * 32 + kb * 8);
      }
    }
    #pragma unroll
    for (int h2 = 0; h2 < 2; ++h2)
      #pragma unroll
      for (int mi = 0; mi < 4; ++mi)
        #pragma unroll
        for (int ni = 0; ni < 2; ++ni)
          acc[mi][ni] = __builtin_amdgcn_mfma_f32_16x16x32_bf16(
              af[h2][mi], bfr[h2][ni], acc[mi][ni], 0, 0, 0);
    __syncthreads();
  }

  #pragma unroll
  for (int mi = 0; mi < 4; ++mi) {
    #pragma unroll
    for (int ni = 0; ni < 2; ++ni) {
      int col = n0 + wn * 32 + ni * 16 + r;
      float bb = bias[col];
      #pragma unroll
      for (int rr = 0; rr < 4; ++rr) {
        long row = m0 + wm * 64 + mi * 16 + kb * 4 + rr;
        float c = acc[mi][ni][rr] + bb;
        if constexpr (MODE == 0) {
          ((bf16*)outp)[row * 576 + col] = __float2bfloat16(c);
        } else {
          long gr = rmap[row];
          ((float*)outp)[gr * 192 + col] = extra[gr * 192 + col] + c;
        }
      }
    }
  }
}

// ---------------- Fused MLP v2 ----------------
// out = h + gelu(LN2(h) @ w1 + b1) @ w2 + b2
// 128 rows/block, 512 threads (8 waves = 4m x 2n). Hidden in 12 chunks of 64.
// Weight chunks staged in LDS (prefetched one chunk ahead, T14-style).
// A-fragments (K=192) held in registers across all chunks.
// All LDS strides pad to bank-offset 4 mod 32 -> only free 2-way conflicts.
#define ALS 200   // Al stride (192+8)
#define W1S 200   // w1 chunk stride (192+8)
#define HLS 72    // Hl stride (64+8)
#define W2S 72    // w2 chunk stride (64+8)
__global__ __launch_bounds__(512) void mlp_k(
    const float* __restrict__ h, const float* __restrict__ g2,
    const float* __restrict__ bg2, const bf16* __restrict__ w1t,
    const float* __restrict__ b1, const bf16* __restrict__ w2t,
    const float* __restrict__ b2, float* __restrict__ outp)
{
  __shared__ bf16 Al[128 * ALS];    // 51200 B
  __shared__ bf16 W1c[64 * W1S];    // 25600 B
  __shared__ bf16 Hl[128 * HLS];    // 18432 B
  __shared__ bf16 W2c[192 * W2S];   // 27648 B   total 122880 B = 120 KB
  const int tid = threadIdx.x;
  const int lane = tid & 63, w = tid >> 6;
  const int wm = w >> 1, wn = w & 1;
  const int r = lane & 15, kb = lane >> 4;
  const long m0 = (long)blockIdx.x * 128;

  // --- issue chunk-0 weight loads ---
  bf16x8 wst[6];
  #pragma unroll
  for (int j = 0; j < 3; ++j) {
    int uu = j * 512 + tid;
    int row = uu / 24, sl = uu - row * 24;
    wst[j] = *(const bf16x8*)(w1t + row * 192 + sl * 8);
  }
  #pragma unroll
  for (int j = 0; j < 3; ++j) {
    int uu = j * 512 + tid;
    int row = uu >> 3, sl = uu & 7;
    wst[3 + j] = *(const bf16x8*)(w2t + row * 768 + sl * 8);
  }

  // --- LN2 into Al: each wave owns 16 rows ---
  {
    float gv0 = g2[lane], gv1 = g2[lane + 64], gv2 = g2[lane + 128];
    float bv0 = bg2[lane], bv1 = bg2[lane + 64], bv2 = bg2[lane + 128];
    #pragma unroll
    for (int half = 0; half < 2; ++half) {
      float va[8][3];
      #pragma unroll
      for (int i = 0; i < 8; ++i) {
        const float* row = h + (m0 + w * 16 + half * 8 + i) * 192;
        va[i][0] = row[lane]; va[i][1] = row[lane + 64]; va[i][2] = row[lane + 128];
      }
      #pragma unroll
      for (int i = 0; i < 8; ++i) {
        float s = va[i][0] + va[i][1] + va[i][2];
        #pragma unroll
        for (int d = 1; d < 64; d <<= 1) s += __shfl_xor(s, d, 64);
        float mu = s * (1.0f / 192.0f);
        float d0 = va[i][0] - mu, d1 = va[i][1] - mu, d2 = va[i][2] - mu;
        float q = d0 * d0 + d1 * d1 + d2 * d2;
        #pragma unroll
        for (int d = 1; d < 64; d <<= 1) q += __shfl_xor(q, d, 64);
        float inv = 1.0f / sqrtf(q * (1.0f / 192.0f) + 1e-5f);
        bf16* o = Al + (w * 16 + half * 8 + i) * ALS;
        o[lane]       = __float2bfloat16(d0 * inv * gv0 + bv0);
        o[lane + 64]  = __float2bfloat16(d1 * inv * gv1 + bv1);
        o[lane + 128] = __float2bfloat16(d2 * inv * gv2 + bv2);
      }
    }
  }

  // --- write chunk-0 weights to LDS ---
  #pragma unroll
  for (int j = 0; j < 3; ++j) {
    int uu = j * 512 + tid;
    int row = uu / 24, sl = uu - row * 24;
    *(bf16x8*)(W1c + row * W1S + sl * 8) = wst[j];
    int row2 = uu >> 3, sl2 = uu & 7;
    *(bf16x8*)(W2c + row2 * W2S + sl2 * 8) = wst[3 + j];
  }
  __syncthreads();

  // --- load A fragments (K=192) into registers, reused by every chunk ---
  bf16x8 af[2][6];
  #pragma unroll
  for (int mi = 0; mi < 2; ++mi)
    #pragma unroll
    for (int ks = 0; ks < 6; ++ks)
      af[mi][ks] = *(const bf16x8*)(Al + (wm * 32 + mi * 16 + r) * ALS + ks * 32 + kb * 8);

  f32x4 oacc[2][6];
  #pragma unroll
  for (int mi = 0; mi < 2; ++mi)
    #pragma unroll
    for (int nj = 0; nj < 6; ++nj) oacc[mi][nj] = (f32x4){0.f, 0.f, 0.f, 0.f};

  for (int c = 0; c < 12; ++c) {
    // fc1: hacc = Al(regs) @ W1c
    f32x4 hacc[2][2];
    #pragma unroll
    for (int mi = 0; mi < 2; ++mi)
      #pragma unroll
      for (int nj = 0; nj < 2; ++nj) hacc[mi][nj] = (f32x4){0.f, 0.f, 0.f, 0.f};
    #pragma unroll
    for (int ks = 0; ks < 6; ++ks) {
      bf16x8 bfr[2];
      #pragma unroll
      for (int nj = 0; nj < 2; ++nj)
        bfr[nj] = *(const bf16x8*)(W1c + (wn * 32 + nj * 16 + r) * W1S + ks * 32 + kb * 8);
      #pragma unroll
      for (int mi = 0; mi < 2; ++mi)
        #pragma unroll
        for (int nj = 0; nj < 2; ++nj)
          hacc[mi][nj] = __builtin_amdgcn_mfma_f32_16x16x32_bf16(af[mi][ks], bfr[nj], hacc[mi][nj], 0, 0, 0);
    }
    // gelu -> Hl
    #pragma unroll
    for (int nj = 0; nj < 2; ++nj) {
      float b1v = b1[c * 64 + wn * 32 + nj * 16 + r];
      #pragma unroll
      for (int mi = 0; mi < 2; ++mi) {
        #pragma unroll
        for (int rr = 0; rr < 4; ++rr) {
          float xv = hacc[mi][nj][rr] + b1v;
          float t = __expf(fmaf(0.0713548162f * xv, xv * xv, 1.5957692f * xv));
          float ge = xv * t / (t + 1.0f);
          Hl[(wm * 32 + mi * 16 + kb * 4 + rr) * HLS + wn * 32 + nj * 16 + r] = __float2bfloat16(ge);
        }
      }
    }
    // prefetch next chunk's weights into registers (latency hides under fc2)
    if (c + 1 < 12) {
      #pragma unroll
      for (int j = 0; j < 3; ++j) {
        int uu = j * 512 + tid;
        int row = uu / 24, sl = uu - row * 24;
        wst[j] = *(const bf16x8*)(w1t + ((c + 1) * 64 + row) * 192 + sl * 8);
      }
      #pragma unroll
      for (int j = 0; j < 3; ++j) {
        int uu = j * 512 + tid;
        int row = uu >> 3, sl = uu & 7;
        wst[3 + j] = *(const bf16x8*)(w2t + row * 768 + (c + 1) * 64 + sl * 8);
      }
    }
    __syncthreads();   // Hl ready; fc1 done with W1c

    // fc2: oacc += Hl @ W2c   (K = 64)
    #pragma unroll
    for (int ks = 0; ks < 2; ++ks) {
      bf16x8 ha[2], wb[6];
      #pragma unroll
      for (int mi = 0; mi < 2; ++mi)
        ha[mi] = *(const bf16x8*)(Hl + (wm * 32 + mi * 16 + r) * HLS + ks * 32 + kb * 8);
      #pragma unroll
      for (int nj = 0; nj < 6; ++nj)
        wb[nj] = *(const bf16x8*)(W2c + (wn * 96 + nj * 16 + r) * W2S + ks * 32 + kb * 8);
      #pragma unroll
      for (int mi = 0; mi < 2; ++mi)
        #pragma unroll
        for (int nj = 0; nj < 6; ++nj)
          oacc[mi][nj] = __builtin_amdgcn_mfma_f32_16x16x32_bf16(ha[mi], wb[nj], oacc[mi][nj], 0, 0, 0);
    }
    __syncthreads();   // fc2 done with W2c & Hl

    if (c + 1 < 12) {
      #pragma unroll
      for (int j = 0; j < 3; ++j) {
        int uu = j * 512 + tid;
        int row = uu / 24, sl = uu - row * 24;
        *(bf16x8*)(W1c + row * W1S + sl * 8) = wst[j];
        int row2 = uu >> 3, sl2 = uu & 7;
        *(bf16x8*)(W2c + row2 * W2S + sl2 * 8) = wst[3 + j];
      }
      __syncthreads();  // new weights visible
    }
  }

  // epilogue: out = h + oacc + b2
  #pragma unroll
  for (int mi = 0; mi < 2; ++mi) {
    #pragma unroll
    for (int nj = 0; nj < 6; ++nj) {
      int col = wn * 96 + nj * 16 + r;
      float b2v = b2[col];
      #pragma unroll
      for (int rr = 0; rr < 4; ++rr) {
        long row = m0 + wm * 32 + mi * 16 + kb * 4 + rr;
        outp[row * 192 + col] = h[row * 192 + col] + oacc[mi][nj][rr] + b2v;
      }
    }
  }
}

// Attention: one wave per (window, head). 49 tokens padded to 64.
__global__ __launch_bounds__(64) void attn_k(
    const bf16* __restrict__ qkv, const float* __restrict__ rpb,
    bf16* __restrict__ aout)
{
  __shared__ bf16 P[64 * 72];
  __shared__ bf16 Vt[32 * 72];
  int lane = threadIdx.x;
  int r = lane & 15, kb = lane >> 4;
  int head = blockIdx.x % 6;
  int win = blockIdx.x / 6;
  int iw = win & 63;
  int wh = iw >> 3, ww = iw & 7;
  const bf16* base = qkv + (long)win * (49 * 576);

  bf16x8 qf[4], kf[4];
  #pragma unroll
  for (int t = 0; t < 4; ++t) {
    int row = t * 16 + r;
    if (row < 49) {
      qf[t] = *(const bf16x8*)(base + row * 576 + head * 32 + kb * 8);
      kf[t] = *(const bf16x8*)(base + row * 576 + 192 + head * 32 + kb * 8);
    } else {
      qf[t] = (bf16x8){0, 0, 0, 0, 0, 0, 0, 0};
      kf[t] = (bf16x8){0, 0, 0, 0, 0, 0, 0, 0};
    }
  }
  f32x4 zero = {0.f, 0.f, 0.f, 0.f};
  f32x4 s[4][4];
  #pragma unroll
  for (int ti = 0; ti < 4; ++ti)
    #pragma unroll
    for (int tj = 0; tj < 4; ++tj)
      s[ti][tj] = __builtin_amdgcn_mfma_f32_16x16x32_bf16(qf[ti], kf[tj], zero, 0, 0, 0);

  {
    int j = lane;
    if (j < 49) {
      #pragma unroll
      for (int d0 = 0; d0 < 32; d0 += 8) {
        bf16x8 v8 = *(const bf16x8*)(base + j * 576 + 384 + head * 32 + d0);
        #pragma unroll
        for (int u = 0; u < 8; ++u) Vt[(d0 + u) * 72 + j] = *((const bf16*)&v8 + u);
      }
    } else {
      for (int d = 0; d < 32; ++d) Vt[d * 72 + j] = __float2bfloat16(0.0f);
    }
  }

  #pragma unroll
  for (int ti = 0; ti < 4; ++ti) {
    #pragma unroll
    for (int rr = 0; rr < 4; ++rr) {
      int i = ti * 16 + kb * 4 + rr;
      int ii = i < 49 ? i : 48;
      int yi = ii / 7, xi = ii - yi * 7;
      int ari = wh * 7 + yi, aci = ww * 7 + xi;
      int gi = (ari < 49 ? 0 : (ari < 53 ? 1 : 2)) * 3 + (aci < 49 ? 0 : (aci < 53 ? 1 : 2));
      float vals[4];
      #pragma unroll
      for (int tj = 0; tj < 4; ++tj) {
        int j = tj * 16 + r;
        int jj = j < 49 ? j : 48;
        int yj = jj / 7, xj = jj - yj * 7;
        float pb = rpb[((yi - yj + 6) * 13 + (xi - xj + 6)) * 6 + head];
        int arj = wh * 7 + yj, acj = ww * 7 + xj;
        int gj = (arj < 49 ? 0 : (arj < 53 ? 1 : 2)) * 3 + (acj < 49 ? 0 : (acj < 53 ? 1 : 2));
        float v = s[ti][tj][rr] * SCALE + pb;
        if (gi != gj) v -= 100.0f;
        if (i >= 49 || j >= 49) v = -1e30f;
        vals[tj] = v;
      }
      float mx = fmaxf(fmaxf(vals[0], vals[1]), fmaxf(vals[2], vals[3]));
      #pragma unroll
      for (int d = 1; d < 16; d <<= 1) mx = fmaxf(mx, __shfl_xor(mx, d, 64));
      float e0 = __expf(vals[0] - mx), e1 = __expf(vals[1] - mx);
      float e2 = __expf(vals[2] - mx), e3 = __expf(vals[3] - mx);
      float sum = e0 + e1 + e2 + e3;
      #pragma unroll
      for (int d = 1; d < 16; d <<= 1) sum += __shfl_xor(sum, d, 64);
      float inv = 1.0f / sum;
      P[i * 72 + 0  + r] = __float2bfloat16(e0 * inv);
      P[i * 72 + 16 + r] = __float2bfloat16(e1 * inv);
      P[i * 72 + 32 + r] = __float2bfloat16(e2 * inv);
      P[i * 72 + 48 + r] = __float2bfloat16(e3 * inv);
    }
  }
  __syncthreads();

  f32x4 o[4][2];
  #pragma unroll
  for (int ti = 0; ti < 4; ++ti)
    #pragma unroll
    for (int dt = 0; dt < 2; ++dt) o[ti][dt] = zero;
  #pragma unroll
  for (int kt = 0; kt < 2; ++kt) {
    bf16x8 pf[4], vf[2];
    #pragma unroll
    for (int ti = 0; ti < 4; ++ti)
      pf[ti] = *(const bf16x8*)(P + (ti * 16 + r) * 72 + kt * 32 + kb * 8);
    #pragma unroll
    for (int dt = 0; dt < 2; ++dt)
      vf[dt] = *(const bf16x8*)(Vt + (dt * 16 + r) * 72 + kt * 32 + kb * 8);
    #pragma unroll
    for (int ti = 0; ti < 4; ++ti)
      #pragma unroll
      for (int dt = 0; dt < 2; ++dt)
        o[ti][dt] = __builtin_amdgcn_mfma_f32_16x16x32_bf16(pf[ti], vf[dt], o[ti][dt], 0, 0, 0);
  }
  #pragma unroll
  for (int ti = 0; ti < 4; ++ti)
    #pragma unroll
    for (int dt = 0; dt < 2; ++dt)
      #pragma unroll
      for (int rr = 0; rr < 4; ++rr) {
        int i = ti * 16 + kb * 4 + rr;
        if (i < 49)
          aout[((long)win * 49 + i) * 192 + head * 32 + dt * 16 + r] =
              __float2bfloat16(o[ti][dt][rr]);
      }
}

extern "C" void kernel_launch(void* const* d_in, const int* in_sizes, int n_in,
                              void* d_out, int out_size, void* d_ws, size_t ws_size,
                              hipStream_t stream)
{
  const float* x      = (const float*)d_in[0];
  const float* qkv_w  = (const float*)d_in[1];
  const float* qkv_b  = (const float*)d_in[2];
  const float* proj_w = (const float*)d_in[3];
  const float* proj_b = (const float*)d_in[4];
  const float* rpb    = (const float*)d_in[5];
  const float* ln1_g  = (const float*)d_in[6];
  const float* ln1_b  = (const float*)d_in[7];
  const float* ln2_g  = (const float*)d_in[8];
  const float* ln2_b  = (const float*)d_in[9];
  const float* w1     = (const float*)d_in[10];
  const float* b1     = (const float*)d_in[11];
  const float* w2     = (const float*)d_in[12];
  const float* b2     = (const float*)d_in[13];

  char* ws = (char*)d_ws;
  bf16* wtq = (bf16*)(ws + OFF_WTQ);
  bf16* wtp = (bf16*)(ws + OFF_WTP);
  bf16* wt1 = (bf16*)(ws + OFF_WT1);
  bf16* wt2 = (bf16*)(ws + OFF_WT2);
  int*  rmap = (int*)(ws + OFF_RMAP);
  bf16* Abuf = (bf16*)(ws + OFF_A);
  bf16* Bbuf = (bf16*)(ws + OFF_B);
  float* hbuf = (float*)(ws + OFF_C);

  prep_k<<<2120, 256, 0, stream>>>(qkv_w, proj_w, w1, w2, wtq, wtp, wt1, wt2, rmap);
  ln_k<true><<<25088, 256, 0, stream>>>(x, ln1_g, ln1_b, rmap, Abuf);
  gemm_k<0, 192><<<dim3(9, 784), 256, 0, stream>>>(Abuf, wtq, qkv_b, nullptr, nullptr, Bbuf);
  attn_k<<<12288, 64, 0, stream>>>(Bbuf, rpb, Abuf);
  gemm_k<1, 192><<<dim3(3, 784), 256, 0, stream>>>(Abuf, wtp, proj_b, x, rmap, hbuf);
  mlp_k<<<784, 512, 0, stream>>>(hbuf, ln2_g, ln2_b, wt1, b1, wt2, b2, (float*)d_out);
}

// Round 8
// 524.466 us; speedup vs baseline: 1.2084x; 1.0048x over previous
//
#include <hip/hip_runtime.h>
#include <hip/hip_bf16.h>
#include <cstdint>

typedef __hip_bfloat16 bf16;
typedef __attribute__((ext_vector_type(4))) float f32x4;
typedef __attribute__((ext_vector_type(8))) __bf16 bf16x8;

#define SCALE 0.17677669529663687f

// ---- workspace offsets (bytes) ----
#define OFF_WTQ   0
#define OFF_WTP   221184
#define OFF_WT1   294912
#define OFF_WT2   589824
#define OFF_RMAP  884736
#define OFF_A     1286144
#define OFF_B     39821312
#define OFF_C     193961984

__global__ __launch_bounds__(256) void prep_k(
    const float* __restrict__ qkv_w, const float* __restrict__ proj_w,
    const float* __restrict__ w1, const float* __restrict__ w2,
    bf16* __restrict__ wtq, bf16* __restrict__ wtp,
    bf16* __restrict__ wt1, bf16* __restrict__ wt2, int* __restrict__ rmap)
{
  int i = blockIdx.x * 256 + threadIdx.x;
  if (i < 110592) {                       // qkv_w (192,576) -> wtq[n][k]
    int n = i / 192, k = i - n * 192;
    wtq[i] = __float2bfloat16(qkv_w[k * 576 + n]);
  } else if (i < 147456) {                // proj_w (192,192)
    int j = i - 110592; int n = j / 192, k = j - n * 192;
    wtp[j] = __float2bfloat16(proj_w[k * 192 + n]);
  } else if (i < 294912) {                // w1 (192,768) -> wt1[768][192]
    int j = i - 147456; int n = j / 192, k = j - n * 192;
    wt1[j] = __float2bfloat16(w1[k * 768 + n]);
  } else if (i < 442368) {                // w2 (768,192) -> wt2[192][768]
    int j = i - 294912; int n = j / 768, k = j - n * 768;
    wt2[j] = __float2bfloat16(w2[k * 192 + n]);
  } else if (i < 542720) {                // rowmap: window row -> natural row
    int m = i - 442368;
    int win = m / 49, nn = m - win * 49;
    int b = win >> 6, iw = win & 63;
    int wh = iw >> 3, ww = iw & 7;
    int ty = nn / 7, tx = nn - ty * 7;
    int rr = wh * 7 + ty + 3; if (rr >= 56) rr -= 56;
    int cc = ww * 7 + tx + 3; if (cc >= 56) cc -= 56;
    rmap[m] = b * 3136 + rr * 56 + cc;
  }
}

// LayerNorm over 192, one wave per row, gather permutation, bf16 out
template<bool MAP>
__global__ __launch_bounds__(256) void ln_k(
    const float* __restrict__ x, const float* __restrict__ g,
    const float* __restrict__ b, const int* __restrict__ rmap,
    bf16* __restrict__ out)
{
  int wv = threadIdx.x >> 6, lane = threadIdx.x & 63;
  long m = (long)blockIdx.x * 4 + wv;
  long src = MAP ? (long)rmap[m] : m;
  const float* row = x + src * 192;
  float v0 = row[lane], v1 = row[lane + 64], v2 = row[lane + 128];
  float s = v0 + v1 + v2;
  #pragma unroll
  for (int d = 1; d < 64; d <<= 1) s += __shfl_xor(s, d, 64);
  float mu = s * (1.0f / 192.0f);
  float d0 = v0 - mu, d1 = v1 - mu, d2 = v2 - mu;
  float q = d0 * d0 + d1 * d1 + d2 * d2;
  #pragma unroll
  for (int d = 1; d < 64; d <<= 1) q += __shfl_xor(q, d, 64);
  float inv = 1.0f / sqrtf(q * (1.0f / 192.0f) + 1e-5f);
  bf16* o = out + m * 192;
  o[lane]       = __float2bfloat16(d0 * inv * g[lane]       + b[lane]);
  o[lane + 64]  = __float2bfloat16(d1 * inv * g[lane + 64]  + b[lane + 64]);
  o[lane + 128] = __float2bfloat16(d2 * inv * g[lane + 128] + b[lane + 128]);
}

// GEMM (single-buffered): C = A @ Wt^T + bias, fused epilogue.
// MODE 0: ->bf16 qkv   1: +x residual scatter ->f32 h
template<int MODE, int KD>
__global__ __launch_bounds__(256) void gemm_k(
    const bf16* __restrict__ A, const bf16* __restrict__ Bt,
    const float* __restrict__ bias, const float* __restrict__ extra,
    const int* __restrict__ rmap, void* __restrict__ outp)
{
  __shared__ bf16 As[128 * 64];
  const int tid = threadIdx.x;
  const int lane = tid & 63;
  const int w = tid >> 6;
  const int wm = w >> 1, wn = w & 1;
  const long m0 = (long)blockIdx.y * 128;
  const int n0 = blockIdx.x * 64;
  const int r = lane & 15, kb = lane >> 4;

  f32x4 acc[4][2];
  #pragma unroll
  for (int a = 0; a < 4; ++a)
    #pragma unroll
    for (int bb = 0; bb < 2; ++bb) acc[a][bb] = (f32x4){0.f, 0.f, 0.f, 0.f};

  for (int k0 = 0; k0 < KD; k0 += 64) {
    #pragma unroll
    for (int it = 0; it < 4; ++it) {
      int li = tid + it * 256;
      int m = li >> 3;
      int sl = (li & 7) ^ (m & 7);
      const bf16* src = A + (m0 + m) * KD + k0 + sl * 8;
      bf16* dst = As + (size_t)(w * 64 + it * 256) * 8;
      __builtin_amdgcn_global_load_lds(
          (const __attribute__((address_space(1))) unsigned int*)src,
          (__attribute__((address_space(3))) unsigned int*)dst, 16, 0, 0);
    }
    __syncthreads();

    bf16x8 af[2][4], bfr[2][2];
    #pragma unroll
    for (int h2 = 0; h2 < 2; ++h2) {
      #pragma unroll
      for (int mi = 0; mi < 4; ++mi) {
        int m = wm * 64 + mi * 16 + r;
        int slot = (h2 * 4 + kb) ^ (r & 7);
        af[h2][mi] = *(const bf16x8*)(As + m * 64 + slot * 8);
      }
      #pragma unroll
      for (int ni = 0; ni < 2; ++ni) {
        int n = n0 + wn * 32 + ni * 16 + r;
        bfr[h2][ni] = *(const bf16x8*)(Bt + (long)n * KD + k0 + h2 * 32 + kb * 8);
      }
    }
    #pragma unroll
    for (int h2 = 0; h2 < 2; ++h2)
      #pragma unroll
      for (int mi = 0; mi < 4; ++mi)
        #pragma unroll
        for (int ni = 0; ni < 2; ++ni)
          acc[mi][ni] = __builtin_amdgcn_mfma_f32_16x16x32_bf16(
              af[h2][mi], bfr[h2][ni], acc[mi][ni], 0, 0, 0);
    __syncthreads();
  }

  #pragma unroll
  for (int mi = 0; mi < 4; ++mi) {
    #pragma unroll
    for (int ni = 0; ni < 2; ++ni) {
      int col = n0 + wn * 32 + ni * 16 + r;
      float bb = bias[col];
      #pragma unroll
      for (int rr = 0; rr < 4; ++rr) {
        long row = m0 + wm * 64 + mi * 16 + kb * 4 + rr;
        float c = acc[mi][ni][rr] + bb;
        if constexpr (MODE == 0) {
          ((bf16*)outp)[row * 576 + col] = __float2bfloat16(c);
        } else {
          long gr = rmap[row];
          ((float*)outp)[gr * 192 + col] = extra[gr * 192 + col] + c;
        }
      }
    }
  }
}

// ---------------- Fused MLP v3 ----------------
// out = h + gelu(LN2(h) @ w1 + b1) @ w2 + b2
// 128 rows/block, 512 threads = 8 waves as 2m x 4n (weight-rep 2, not 4).
// Hidden in 12 chunks of 64. Weight chunks double-buffered; buffer 1 aliases
// Al's region (Al dead after A-fragments move to registers). 2 barriers/chunk.
// All LDS rows are multiples of 32 dwords (no pad); XOR-unit swizzle
// (16B unit ^= row&7) makes every 16-lane fragment read conflict-free.
__global__ __launch_bounds__(512, 2) void mlp_k(
    const float* __restrict__ h, const float* __restrict__ g2,
    const float* __restrict__ bg2, const bf16* __restrict__ w1t,
    const float* __restrict__ b1, const bf16* __restrict__ w2t,
    const float* __restrict__ b2, float* __restrict__ outp)
{
  // layout: [0,49152) Al (prologue) / wbuf1 (W1c1 @0, W2c1 @24576)
  //         [49152,73728) W1c0   [73728,98304) W2c0   [98304,114688) Hl
  __shared__ __align__(16) char smem[114688];
  bf16* const Al = (bf16*)smem;
  bf16* const Hl = (bf16*)(smem + 98304);
  const int tid = threadIdx.x;
  const int lane = tid & 63, w = tid >> 6;
  const int wm2 = w >> 2, wn4 = w & 3;
  const int r = lane & 15, kb = lane >> 4;
  const long m0 = (long)blockIdx.x * 128;

  // --- issue chunk-0 weight loads ---
  bf16x8 wst[6];
  #pragma unroll
  for (int j = 0; j < 3; ++j) {
    int uu = j * 512 + tid;
    int row = uu / 24, sl = uu - row * 24;
    wst[j] = *(const bf16x8*)(w1t + row * 192 + sl * 8);
    int row2 = uu >> 3, sl2 = uu & 7;
    wst[3 + j] = *(const bf16x8*)(w2t + row2 * 768 + sl2 * 8);
  }

  // --- LN2 -> Al (swizzled units) ---
  {
    float gv0 = g2[lane], gv1 = g2[lane + 64], gv2 = g2[lane + 128];
    float bv0 = bg2[lane], bv1 = bg2[lane + 64], bv2 = bg2[lane + 128];
    int u0 = lane >> 3, cl = lane & 7;
    #pragma unroll
    for (int half = 0; half < 2; ++half) {
      float va[8][3];
      #pragma unroll
      for (int i = 0; i < 8; ++i) {
        const float* row = h + (m0 + w * 16 + half * 8 + i) * 192;
        va[i][0] = row[lane]; va[i][1] = row[lane + 64]; va[i][2] = row[lane + 128];
      }
      #pragma unroll
      for (int i = 0; i < 8; ++i) {
        int rowi = w * 16 + half * 8 + i;
        float s = va[i][0] + va[i][1] + va[i][2];
        #pragma unroll
        for (int d = 1; d < 64; d <<= 1) s += __shfl_xor(s, d, 64);
        float mu = s * (1.0f / 192.0f);
        float d0 = va[i][0] - mu, d1 = va[i][1] - mu, d2 = va[i][2] - mu;
        float q = d0 * d0 + d1 * d1 + d2 * d2;
        #pragma unroll
        for (int d = 1; d < 64; d <<= 1) q += __shfl_xor(q, d, 64);
        float inv = 1.0f / sqrtf(q * (1.0f / 192.0f) + 1e-5f);
        bf16* o = Al + rowi * 192;
        int rx = rowi & 7;
        o[((u0 ^ rx) << 3) + cl]              = __float2bfloat16(d0 * inv * gv0 + bv0);
        o[((8 | ((u0 ^ rx) & 7)) << 3) + cl]  = __float2bfloat16(d1 * inv * gv1 + bv1);
        o[((16 | ((u0 ^ rx) & 7)) << 3) + cl] = __float2bfloat16(d2 * inv * gv2 + bv2);
      }
    }
  }

  // --- write chunk-0 weights to buffer 0 ---
  {
    bf16* W1c = (bf16*)(smem + 49152);
    bf16* W2c = (bf16*)(smem + 73728);
    #pragma unroll
    for (int j = 0; j < 3; ++j) {
      int uu = j * 512 + tid;
      int row = uu / 24, u = uu - row * 24;
      int up = (u & ~7) | ((u ^ row) & 7);
      *(bf16x8*)(W1c + row * 192 + up * 8) = wst[j];
      int row2 = uu >> 3, u2 = uu & 7;
      *(bf16x8*)(W2c + row2 * 64 + ((u2 ^ (row2 & 7)) << 3)) = wst[3 + j];
    }
  }
  __syncthreads();

  // --- A fragments: 64 rows per wave, K=192, register-resident for all chunks ---
  bf16x8 af[4][6];
  #pragma unroll
  for (int mt = 0; mt < 4; ++mt) {
    int row = wm2 * 64 + mt * 16 + r;
    #pragma unroll
    for (int ks = 0; ks < 6; ++ks) {
      int u = ks * 4 + kb;
      int up = (u & ~7) | ((u ^ row) & 7);
      af[mt][ks] = *(const bf16x8*)(Al + row * 192 + up * 8);
    }
  }

  f32x4 oacc[4][3];
  #pragma unroll
  for (int mt = 0; mt < 4; ++mt)
    #pragma unroll
    for (int nt = 0; nt < 3; ++nt) oacc[mt][nt] = (f32x4){0.f, 0.f, 0.f, 0.f};

  for (int c = 0; c < 12; ++c) {
    bf16* W1c = (bf16*)(smem + ((c & 1) ? 0 : 49152));
    bf16* W2c = (bf16*)(smem + ((c & 1) ? 24576 : 73728));

    // fc1 B-fragments (16 cols per wave)
    bf16x8 bfr[6];
    {
      int row = wn4 * 16 + r;
      #pragma unroll
      for (int ks = 0; ks < 6; ++ks) {
        int u = ks * 4 + kb;
        int up = (u & ~7) | ((u ^ row) & 7);
        bfr[ks] = *(const bf16x8*)(W1c + row * 192 + up * 8);
      }
    }
    // issue next-chunk weight loads (latency hidden under fc1+gelu+fc2)
    if (c + 1 < 12) {
      #pragma unroll
      for (int j = 0; j < 3; ++j) {
        int uu = j * 512 + tid;
        int row = uu / 24, sl = uu - row * 24;
        wst[j] = *(const bf16x8*)(w1t + ((c + 1) * 64 + row) * 192 + sl * 8);
        int row2 = uu >> 3, sl2 = uu & 7;
        wst[3 + j] = *(const bf16x8*)(w2t + row2 * 768 + (c + 1) * 64 + sl2 * 8);
      }
    }
    // fc1: 64 rows x 16 cols per wave
    f32x4 hacc[4];
    #pragma unroll
    for (int mt = 0; mt < 4; ++mt) hacc[mt] = (f32x4){0.f, 0.f, 0.f, 0.f};
    #pragma unroll
    for (int ks = 0; ks < 6; ++ks)
      #pragma unroll
      for (int mt = 0; mt < 4; ++mt)
        hacc[mt] = __builtin_amdgcn_mfma_f32_16x16x32_bf16(af[mt][ks], bfr[ks], hacc[mt], 0, 0, 0);
    // gelu -> Hl (swizzled)
    {
      float b1v = b1[c * 64 + wn4 * 16 + r];
      #pragma unroll
      for (int mt = 0; mt < 4; ++mt) {
        #pragma unroll
        for (int rr = 0; rr < 4; ++rr) {
          int row = wm2 * 64 + mt * 16 + kb * 4 + rr;
          int col = wn4 * 16 + r;
          float xv = hacc[mt][rr] + b1v;
          float t = __expf(fmaf(0.0713548162f * xv, xv * xv, 1.5957692f * xv));
          float ge = xv * t / (t + 1.0f);
          Hl[row * 64 + (((col >> 3) ^ (row & 7)) << 3) + (col & 7)] = __float2bfloat16(ge);
        }
      }
    }
    __syncthreads();                 // A: Hl visible, fc1 done with W1c

    // fc2: 64 rows x 48 cols per wave, K=64
    #pragma unroll
    for (int ks = 0; ks < 2; ++ks) {
      bf16x8 ha[4], wb[3];
      #pragma unroll
      for (int mt = 0; mt < 4; ++mt) {
        int row = wm2 * 64 + mt * 16 + r;
        ha[mt] = *(const bf16x8*)(Hl + row * 64 + (((ks * 4 + kb) ^ (row & 7)) << 3));
      }
      #pragma unroll
      for (int nt = 0; nt < 3; ++nt) {
        int n = wn4 * 48 + nt * 16 + r;
        wb[nt] = *(const bf16x8*)(W2c + n * 64 + (((ks * 4 + kb) ^ (n & 7)) << 3));
      }
      #pragma unroll
      for (int mt = 0; mt < 4; ++mt)
        #pragma unroll
        for (int nt = 0; nt < 3; ++nt)
          oacc[mt][nt] = __builtin_amdgcn_mfma_f32_16x16x32_bf16(ha[mt], wb[nt], oacc[mt][nt], 0, 0, 0);
    }
    // write next-chunk weights to the other buffer (disjoint from readers)
    if (c + 1 < 12) {
      bf16* nW1 = (bf16*)(smem + ((c & 1) ? 49152 : 0));
      bf16* nW2 = (bf16*)(smem + ((c & 1) ? 73728 : 24576));
      #pragma unroll
      for (int j = 0; j < 3; ++j) {
        int uu = j * 512 + tid;
        int row = uu / 24, u = uu - row * 24;
        int up = (u & ~7) | ((u ^ row) & 7);
        *(bf16x8*)(nW1 + row * 192 + up * 8) = wst[j];
        int row2 = uu >> 3, u2 = uu & 7;
        *(bf16x8*)(nW2 + row2 * 64 + ((u2 ^ (row2 & 7)) << 3)) = wst[3 + j];
      }
    }
    __syncthreads();                 // B: fc2 done, next weights visible
  }

  // epilogue: out = h + oacc + b2
  #pragma unroll
  for (int mt = 0; mt < 4; ++mt) {
    #pragma unroll
    for (int nt = 0; nt < 3; ++nt) {
      int col = wn4 * 48 + nt * 16 + r;
      float b2v = b2[col];
      #pragma unroll
      for (int rr = 0; rr < 4; ++rr) {
        long row = m0 + wm2 * 64 + mt * 16 + kb * 4 + rr;
        outp[row * 192 + col] = h[row * 192 + col] + oacc[mt][nt][rr] + b2v;
      }
    }
  }
}

// Attention: one wave per (window, head). 49 tokens padded to 64.
__global__ __launch_bounds__(64) void attn_k(
    const bf16* __restrict__ qkv, const float* __restrict__ rpb,
    bf16* __restrict__ aout)
{
  __shared__ bf16 P[64 * 72];
  __shared__ bf16 Vt[32 * 72];
  int lane = threadIdx.x;
  int r = lane & 15, kb = lane >> 4;
  int head = blockIdx.x % 6;
  int win = blockIdx.x / 6;
  int iw = win & 63;
  int wh = iw >> 3, ww = iw & 7;
  const bf16* base = qkv + (long)win * (49 * 576);

  bf16x8 qf[4], kf[4];
  #pragma unroll
  for (int t = 0; t < 4; ++t) {
    int row = t * 16 + r;
    if (row < 49) {
      qf[t] = *(const bf16x8*)(base + row * 576 + head * 32 + kb * 8);
      kf[t] = *(const bf16x8*)(base + row * 576 + 192 + head * 32 + kb * 8);
    } else {
      qf[t] = (bf16x8){0, 0, 0, 0, 0, 0, 0, 0};
      kf[t] = (bf16x8){0, 0, 0, 0, 0, 0, 0, 0};
    }
  }
  f32x4 zero = {0.f, 0.f, 0.f, 0.f};
  f32x4 s[4][4];
  #pragma unroll
  for (int ti = 0; ti < 4; ++ti)
    #pragma unroll
    for (int tj = 0; tj < 4; ++tj)
      s[ti][tj] = __builtin_amdgcn_mfma_f32_16x16x32_bf16(qf[ti], kf[tj], zero, 0, 0, 0);

  {
    int j = lane;
    if (j < 49) {
      #pragma unroll
      for (int d0 = 0; d0 < 32; d0 += 8) {
        bf16x8 v8 = *(const bf16x8*)(base + j * 576 + 384 + head * 32 + d0);
        #pragma unroll
        for (int u = 0; u < 8; ++u) Vt[(d0 + u) * 72 + j] = *((const bf16*)&v8 + u);
      }
    } else {
      for (int d = 0; d < 32; ++d) Vt[d * 72 + j] = __float2bfloat16(0.0f);
    }
  }

  #pragma unroll
  for (int ti = 0; ti < 4; ++ti) {
    #pragma unroll
    for (int rr = 0; rr < 4; ++rr) {
      int i = ti * 16 + kb * 4 + rr;
      int ii = i < 49 ? i : 48;
      int yi = ii / 7, xi = ii - yi * 7;
      int ari = wh * 7 + yi, aci = ww * 7 + xi;
      int gi = (ari < 49 ? 0 : (ari < 53 ? 1 : 2)) * 3 + (aci < 49 ? 0 : (aci < 53 ? 1 : 2));
      float vals[4];
      #pragma unroll
      for (int tj = 0; tj < 4; ++tj) {
        int j = tj * 16 + r;
        int jj = j < 49 ? j : 48;
        int yj = jj / 7, xj = jj - yj * 7;
        float pb = rpb[((yi - yj + 6) * 13 + (xi - xj + 6)) * 6 + head];
        int arj = wh * 7 + yj, acj = ww * 7 + xj;
        int gj = (arj < 49 ? 0 : (arj < 53 ? 1 : 2)) * 3 + (acj < 49 ? 0 : (acj < 53 ? 1 : 2));
        float v = s[ti][tj][rr] * SCALE + pb;
        if (gi != gj) v -= 100.0f;
        if (i >= 49 || j >= 49) v = -1e30f;
        vals[tj] = v;
      }
      float mx = fmaxf(fmaxf(vals[0], vals[1]), fmaxf(vals[2], vals[3]));
      #pragma unroll
      for (int d = 1; d < 16; d <<= 1) mx = fmaxf(mx, __shfl_xor(mx, d, 64));
      float e0 = __expf(vals[0] - mx), e1 = __expf(vals[1] - mx);
      float e2 = __expf(vals[2] - mx), e3 = __expf(vals[3] - mx);
      float sum = e0 + e1 + e2 + e3;
      #pragma unroll
      for (int d = 1; d < 16; d <<= 1) sum += __shfl_xor(sum, d, 64);
      float inv = 1.0f / sum;
      P[i * 72 + 0  + r] = __float2bfloat16(e0 * inv);
      P[i * 72 + 16 + r] = __float2bfloat16(e1 * inv);
      P[i * 72 + 32 + r] = __float2bfloat16(e2 * inv);
      P[i * 72 + 48 + r] = __float2bfloat16(e3 * inv);
    }
  }
  __syncthreads();

  f32x4 o[4][2];
  #pragma unroll
  for (int ti = 0; ti < 4; ++ti)
    #pragma unroll
    for (int dt = 0; dt < 2; ++dt) o[ti][dt] = zero;
  #pragma unroll
  for (int kt = 0; kt < 2; ++kt) {
    bf16x8 pf[4], vf[2];
    #pragma unroll
    for (int ti = 0; ti < 4; ++ti)
      pf[ti] = *(const bf16x8*)(P + (ti * 16 + r) * 72 + kt * 32 + kb * 8);
    #pragma unroll
    for (int dt = 0; dt < 2; ++dt)
      vf[dt] = *(const bf16x8*)(Vt + (dt * 16 + r) * 72 + kt * 32 + kb * 8);
    #pragma unroll
    for (int ti = 0; ti < 4; ++ti)
      #pragma unroll
      for (int dt = 0; dt < 2; ++dt)
        o[ti][dt] = __builtin_amdgcn_mfma_f32_16x16x32_bf16(pf[ti], vf[dt], o[ti][dt], 0, 0, 0);
  }
  #pragma unroll
  for (int ti = 0; ti < 4; ++ti)
    #pragma unroll
    for (int dt = 0; dt < 2; ++dt)
      #pragma unroll
      for (int rr = 0; rr < 4; ++rr) {
        int i = ti * 16 + kb * 4 + rr;
        if (i < 49)
          aout[((long)win * 49 + i) * 192 + head * 32 + dt * 16 + r] =
              __float2bfloat16(o[ti][dt][rr]);
      }
}

extern "C" void kernel_launch(void* const* d_in, const int* in_sizes, int n_in,
                              void* d_out, int out_size, void* d_ws, size_t ws_size,
                              hipStream_t stream)
{
  const float* x      = (const float*)d_in[0];
  const float* qkv_w  = (const float*)d_in[1];
  const float* qkv_b  = (const float*)d_in[2];
  const float* proj_w = (const float*)d_in[3];
  const float* proj_b = (const float*)d_in[4];
  const float* rpb    = (const float*)d_in[5];
  const float* ln1_g  = (const float*)d_in[6];
  const float* ln1_b  = (const float*)d_in[7];
  const float* ln2_g  = (const float*)d_in[8];
  const float* ln2_b  = (const float*)d_in[9];
  const float* w1     = (const float*)d_in[10];
  const float* b1     = (const float*)d_in[11];
  const float* w2     = (const float*)d_in[12];
  const float* b2     = (const float*)d_in[13];

  char* ws = (char*)d_ws;
  bf16* wtq = (bf16*)(ws + OFF_WTQ);
  bf16* wtp = (bf16*)(ws + OFF_WTP);
  bf16* wt1 = (bf16*)(ws + OFF_WT1);
  bf16* wt2 = (bf16*)(ws + OFF_WT2);
  int*  rmap = (int*)(ws + OFF_RMAP);
  bf16* Abuf = (bf16*)(ws + OFF_A);
  bf16* Bbuf = (bf16*)(ws + OFF_B);
  float* hbuf = (float*)(ws + OFF_C);

  prep_k<<<2120, 256, 0, stream>>>(qkv_w, proj_w, w1, w2, wtq, wtp, wt1, wt2, rmap);
  ln_k<true><<<25088, 256, 0, stream>>>(x, ln1_g, ln1_b, rmap, Abuf);
  gemm_k<0, 192><<<dim3(9, 784), 256, 0, stream>>>(Abuf, wtq, qkv_b, nullptr, nullptr, Bbuf);
  attn_k<<<12288, 64, 0, stream>>>(Bbuf, rpb, Abuf);
  gemm_k<1, 192><<<dim3(3, 784), 256, 0, stream>>>(Abuf, wtp, proj_b, x, rmap, hbuf);
  mlp_k<<<784, 512, 0, stream>>>(hbuf, ln2_g, ln2_b, wt1, b1, wt2, b2, (float*)d_out);
}

// Round 9
// 474.496 us; speedup vs baseline: 1.3357x; 1.1053x over previous
//
#include <hip/hip_runtime.h>
#include <hip/hip_bf16.h>
#include <cstdint>

typedef __hip_bfloat16 bf16;
typedef __attribute__((ext_vector_type(4))) float f32x4;
typedef __attribute__((ext_vector_type(8))) __bf16 bf16x8;

#define SCALE 0.17677669529663687f

// ---- workspace offsets (bytes) ----
#define OFF_WTQ   0
#define OFF_WTP   221184
#define OFF_WT1   294912
#define OFF_WT2   589824
#define OFF_RMAP  884736
#define OFF_A     1286144
#define OFF_B     39821312
#define OFF_C     193961984

__global__ __launch_bounds__(256) void prep_k(
    const float* __restrict__ qkv_w, const float* __restrict__ proj_w,
    const float* __restrict__ w1, const float* __restrict__ w2,
    bf16* __restrict__ wtq, bf16* __restrict__ wtp,
    bf16* __restrict__ wt1, bf16* __restrict__ wt2, int* __restrict__ rmap)
{
  int i = blockIdx.x * 256 + threadIdx.x;
  if (i < 110592) {                       // qkv_w (192,576) -> wtq[n][k]
    int n = i / 192, k = i - n * 192;
    wtq[i] = __float2bfloat16(qkv_w[k * 576 + n]);
  } else if (i < 147456) {                // proj_w (192,192)
    int j = i - 110592; int n = j / 192, k = j - n * 192;
    wtp[j] = __float2bfloat16(proj_w[k * 192 + n]);
  } else if (i < 294912) {                // w1 (192,768) -> wt1[768][192]
    int j = i - 147456; int n = j / 192, k = j - n * 192;
    wt1[j] = __float2bfloat16(w1[k * 768 + n]);
  } else if (i < 442368) {                // w2 (768,192) -> wt2[192][768]
    int j = i - 294912; int n = j / 768, k = j - n * 768;
    wt2[j] = __float2bfloat16(w2[k * 192 + n]);
  } else if (i < 542720) {                // rowmap: window row -> natural row
    int m = i - 442368;
    int win = m / 49, nn = m - win * 49;
    int b = win >> 6, iw = win & 63;
    int wh = iw >> 3, ww = iw & 7;
    int ty = nn / 7, tx = nn - ty * 7;
    int rr = wh * 7 + ty + 3; if (rr >= 56) rr -= 56;
    int cc = ww * 7 + tx + 3; if (cc >= 56) cc -= 56;
    rmap[m] = b * 3136 + rr * 56 + cc;
  }
}

// LayerNorm over 192, one wave per row, gather permutation, bf16 out
template<bool MAP>
__global__ __launch_bounds__(256) void ln_k(
    const float* __restrict__ x, const float* __restrict__ g,
    const float* __restrict__ b, const int* __restrict__ rmap,
    bf16* __restrict__ out)
{
  int wv = threadIdx.x >> 6, lane = threadIdx.x & 63;
  long m = (long)blockIdx.x * 4 + wv;
  long src = MAP ? (long)rmap[m] : m;
  const float* row = x + src * 192;
  float v0 = row[lane], v1 = row[lane + 64], v2 = row[lane + 128];
  float s = v0 + v1 + v2;
  #pragma unroll
  for (int d = 1; d < 64; d <<= 1) s += __shfl_xor(s, d, 64);
  float mu = s * (1.0f / 192.0f);
  float d0 = v0 - mu, d1 = v1 - mu, d2 = v2 - mu;
  float q = d0 * d0 + d1 * d1 + d2 * d2;
  #pragma unroll
  for (int d = 1; d < 64; d <<= 1) q += __shfl_xor(q, d, 64);
  float inv = 1.0f / sqrtf(q * (1.0f / 192.0f) + 1e-5f);
  bf16* o = out + m * 192;
  o[lane]       = __float2bfloat16(d0 * inv * g[lane]       + b[lane]);
  o[lane + 64]  = __float2bfloat16(d1 * inv * g[lane + 64]  + b[lane + 64]);
  o[lane + 128] = __float2bfloat16(d2 * inv * g[lane + 128] + b[lane + 128]);
}

// GEMM (single-buffered): C = A @ Wt^T + bias, fused epilogue.
// MODE 0: ->bf16 qkv   1: +x residual scatter ->f32 h
template<int MODE, int KD>
__global__ __launch_bounds__(256) void gemm_k(
    const bf16* __restrict__ A, const bf16* __restrict__ Bt,
    const float* __restrict__ bias, const float* __restrict__ extra,
    const int* __restrict__ rmap, void* __restrict__ outp)
{
  __shared__ bf16 As[128 * 64];
  const int tid = threadIdx.x;
  const int lane = tid & 63;
  const int w = tid >> 6;
  const int wm = w >> 1, wn = w & 1;
  const long m0 = (long)blockIdx.y * 128;
  const int n0 = blockIdx.x * 64;
  const int r = lane & 15, kb = lane >> 4;

  f32x4 acc[4][2];
  #pragma unroll
  for (int a = 0; a < 4; ++a)
    #pragma unroll
    for (int bb = 0; bb < 2; ++bb) acc[a][bb] = (f32x4){0.f, 0.f, 0.f, 0.f};

  for (int k0 = 0; k0 < KD; k0 += 64) {
    #pragma unroll
    for (int it = 0; it < 4; ++it) {
      int li = tid + it * 256;
      int m = li >> 3;
      int sl = (li & 7) ^ (m & 7);
      const bf16* src = A + (m0 + m) * KD + k0 + sl * 8;
      bf16* dst = As + (size_t)(w * 64 + it * 256) * 8;
      __builtin_amdgcn_global_load_lds(
          (const __attribute__((address_space(1))) unsigned int*)src,
          (__attribute__((address_space(3))) unsigned int*)dst, 16, 0, 0);
    }
    __syncthreads();

    bf16x8 af[2][4], bfr[2][2];
    #pragma unroll
    for (int h2 = 0; h2 < 2; ++h2) {
      #pragma unroll
      for (int mi = 0; mi < 4; ++mi) {
        int m = wm * 64 + mi * 16 + r;
        int slot = (h2 * 4 + kb) ^ (r & 7);
        af[h2][mi] = *(const bf16x8*)(As + m * 64 + slot * 8);
      }
      #pragma unroll
      for (int ni = 0; ni < 2; ++ni) {
        int n = n0 + wn * 32 + ni * 16 + r;
        bfr[h2][ni] = *(const bf16x8*)(Bt + (long)n * KD + k0 + h2 * 32 + kb * 8);
      }
    }
    #pragma unroll
    for (int h2 = 0; h2 < 2; ++h2)
      #pragma unroll
      for (int mi = 0; mi < 4; ++mi)
        #pragma unroll
        for (int ni = 0; ni < 2; ++ni)
          acc[mi][ni] = __builtin_amdgcn_mfma_f32_16x16x32_bf16(
              af[h2][mi], bfr[h2][ni], acc[mi][ni], 0, 0, 0);
    __syncthreads();
  }

  #pragma unroll
  for (int mi = 0; mi < 4; ++mi) {
    #pragma unroll
    for (int ni = 0; ni < 2; ++ni) {
      int col = n0 + wn * 32 + ni * 16 + r;
      float bb = bias[col];
      #pragma unroll
      for (int rr = 0; rr < 4; ++rr) {
        long row = m0 + wm * 64 + mi * 16 + kb * 4 + rr;
        float c = acc[mi][ni][rr] + bb;
        if constexpr (MODE == 0) {
          ((bf16*)outp)[row * 576 + col] = __float2bfloat16(c);
        } else {
          long gr = rmap[row];
          ((float*)outp)[gr * 192 + col] = extra[gr * 192 + col] + c;
        }
      }
    }
  }
}

// ---------------- Fused MLP v4 ----------------
// out = h + gelu(LN2(h) @ w1 + b1) @ w2 + b2
// 64 rows/block, 256 threads (4 waves = 2m x 2n). Hidden in 24 chunks of 32.
// LDS 53248 B -> 3 blocks/CU (12 waves/CU). Weight chunks double-buffered,
// staged via global_load_lds with PRE-SWIZZLED SOURCE addresses (linear LDS
// dest); buf1 aliases Al (dead after af regs loaded). gelu uses rcp intrinsic.
// LDS: Al @0 (24576) | W1c0 @24576 (12288) | W2c0 @36864 (12288) | Hl @49152 (4096)
//      buf1: W1c1 @0, W2c1 @12288
__global__ __launch_bounds__(256, 3) void mlp_k(
    const float* __restrict__ h, const float* __restrict__ g2,
    const float* __restrict__ bg2, const bf16* __restrict__ w1t,
    const float* __restrict__ b1, const bf16* __restrict__ w2t,
    const float* __restrict__ b2, float* __restrict__ outp)
{
  __shared__ __align__(16) char smem[53248];
  bf16* const Al = (bf16*)smem;
  bf16* const Hl = (bf16*)(smem + 49152);
  const int tid = threadIdx.x;
  const int lane = tid & 63, w = tid >> 6;
  const int wm = w >> 1, wn = w & 1;
  const int r = lane & 15, kb = lane >> 4;
  const long m0 = (long)blockIdx.x * 64;

  // stage weight chunk c into (base1=W1c, base2=W2c) via global_load_lds.
  // W1c: 32x192 row-major, unit(16B) v=row*24+s'; stored value from slot
  // s=(s'&~7)|((s'^row)&7) (XOR involution). W2c: 192x32, unit v=n*4+s';
  // k-slot = s'^((n>>1)&3).
  auto stageW = [&](int c, int base1, int base2) {
    #pragma unroll
    for (int j = 0; j < 3; ++j) {
      int v = j * 256 + tid;
      int row = v / 24, s1 = v - row * 24;
      int ss = (s1 & ~7) | ((s1 ^ row) & 7);
      const bf16* src1 = w1t + (c * 32 + row) * 192 + ss * 8;
      bf16* dst1 = (bf16*)(smem + base1) + (size_t)(w * 64 + j * 256) * 8;
      __builtin_amdgcn_global_load_lds(
          (const __attribute__((address_space(1))) unsigned int*)src1,
          (__attribute__((address_space(3))) unsigned int*)dst1, 16, 0, 0);
      int n = v >> 2, s2 = v & 3;
      int kk = s2 ^ ((n >> 1) & 3);
      const bf16* src2 = w2t + n * 768 + c * 32 + kk * 8;
      bf16* dst2 = (bf16*)(smem + base2) + (size_t)(w * 64 + j * 256) * 8;
      __builtin_amdgcn_global_load_lds(
          (const __attribute__((address_space(1))) unsigned int*)src2,
          (__attribute__((address_space(3))) unsigned int*)dst2, 16, 0, 0);
    }
  };

  stageW(0, 24576, 36864);   // buf0; latency hides under LN

  // --- LN2 -> Al (swizzled units), each wave 16 rows ---
  {
    float gv0 = g2[lane], gv1 = g2[lane + 64], gv2 = g2[lane + 128];
    float bv0 = bg2[lane], bv1 = bg2[lane + 64], bv2 = bg2[lane + 128];
    int u0 = lane >> 3, cl = lane & 7;
    #pragma unroll
    for (int half = 0; half < 2; ++half) {
      float va[8][3];
      #pragma unroll
      for (int i = 0; i < 8; ++i) {
        const float* row = h + (m0 + w * 16 + half * 8 + i) * 192;
        va[i][0] = row[lane]; va[i][1] = row[lane + 64]; va[i][2] = row[lane + 128];
      }
      #pragma unroll
      for (int i = 0; i < 8; ++i) {
        int rowi = w * 16 + half * 8 + i;
        float s = va[i][0] + va[i][1] + va[i][2];
        #pragma unroll
        for (int d = 1; d < 64; d <<= 1) s += __shfl_xor(s, d, 64);
        float mu = s * (1.0f / 192.0f);
        float d0 = va[i][0] - mu, d1 = va[i][1] - mu, d2 = va[i][2] - mu;
        float q = d0 * d0 + d1 * d1 + d2 * d2;
        #pragma unroll
        for (int d = 1; d < 64; d <<= 1) q += __shfl_xor(q, d, 64);
        float inv = 1.0f / sqrtf(q * (1.0f / 192.0f) + 1e-5f);
        bf16* o = Al + rowi * 192;
        int rx = rowi & 7;
        o[((u0 ^ rx) << 3) + cl]              = __float2bfloat16(d0 * inv * gv0 + bv0);
        o[((8 | ((u0 ^ rx) & 7)) << 3) + cl]  = __float2bfloat16(d1 * inv * gv1 + bv1);
        o[((16 | ((u0 ^ rx) & 7)) << 3) + cl] = __float2bfloat16(d2 * inv * gv2 + bv2);
      }
    }
  }
  __syncthreads();   // Al + buf0 ready

  // --- A fragments: 32 rows per wave, K=192, register-resident ---
  bf16x8 af[2][6];
  #pragma unroll
  for (int mt = 0; mt < 2; ++mt) {
    int row = wm * 32 + mt * 16 + r;
    #pragma unroll
    for (int ks = 0; ks < 6; ++ks) {
      int u = ks * 4 + kb;
      int up = (u & ~7) | ((u ^ row) & 7);
      af[mt][ks] = *(const bf16x8*)(Al + row * 192 + up * 8);
    }
  }
  // af in flight; ensure the ds_reads retired before buf1 gloads can overwrite Al
  asm volatile("s_waitcnt lgkmcnt(0)" ::: "memory");

  f32x4 oacc[2][6];
  #pragma unroll
  for (int mt = 0; mt < 2; ++mt)
    #pragma unroll
    for (int nt = 0; nt < 6; ++nt) oacc[mt][nt] = (f32x4){0.f, 0.f, 0.f, 0.f};

  for (int c = 0; c < 24; ++c) {
    const int cb = c & 1;
    bf16* W1c = (bf16*)(smem + (cb ? 0 : 24576));
    bf16* W2c = (bf16*)(smem + (cb ? 12288 : 36864));
    if (c + 1 < 24) stageW(c + 1, cb ? 24576 : 0, cb ? 36864 : 12288);

    // fc1: 32 rows x 16 cols per wave (K=192)
    bf16x8 bfr[6];
    {
      int brow = wn * 16 + r;
      #pragma unroll
      for (int ks = 0; ks < 6; ++ks) {
        int u = ks * 4 + kb;
        int up = (u & ~7) | ((u ^ brow) & 7);
        bfr[ks] = *(const bf16x8*)(W1c + brow * 192 + up * 8);
      }
    }
    f32x4 hacc[2];
    #pragma unroll
    for (int mt = 0; mt < 2; ++mt) hacc[mt] = (f32x4){0.f, 0.f, 0.f, 0.f};
    #pragma unroll
    for (int ks = 0; ks < 6; ++ks)
      #pragma unroll
      for (int mt = 0; mt < 2; ++mt)
        hacc[mt] = __builtin_amdgcn_mfma_f32_16x16x32_bf16(af[mt][ks], bfr[ks], hacc[mt], 0, 0, 0);

    // gelu -> Hl (unit = row*4 + ((col>>3)^((row>>1)&3)))
    {
      float b1v = b1[c * 32 + wn * 16 + r];
      int col = wn * 16 + r;
      #pragma unroll
      for (int mt = 0; mt < 2; ++mt) {
        #pragma unroll
        for (int rr = 0; rr < 4; ++rr) {
          int row = wm * 32 + mt * 16 + kb * 4 + rr;
          float xv = hacc[mt][rr] + b1v;
          float z = xv * fmaf(0.0713548162f, xv * xv, 1.5957692f);
          float t = __expf(z);
          float ge = xv * t * __builtin_amdgcn_rcpf(t + 1.0f);
          int un = row * 4 + ((col >> 3) ^ ((row >> 1) & 3));
          Hl[un * 8 + (col & 7)] = __float2bfloat16(ge);
        }
      }
    }
    __syncthreads();   // A: Hl visible; buf^1 gloads drained (vmcnt)

    // fc2: 32 rows x 96 cols per wave, K=32
    {
      bf16x8 ha[2], wb[6];
      #pragma unroll
      for (int mt = 0; mt < 2; ++mt) {
        int row = wm * 32 + mt * 16 + r;
        ha[mt] = *(const bf16x8*)(Hl + (row * 4 + (kb ^ ((row >> 1) & 3))) * 8);
      }
      #pragma unroll
      for (int nt = 0; nt < 6; ++nt) {
        int n = wn * 96 + nt * 16 + r;
        wb[nt] = *(const bf16x8*)(W2c + (n * 4 + (kb ^ ((n >> 1) & 3))) * 8);
      }
      #pragma unroll
      for (int mt = 0; mt < 2; ++mt)
        #pragma unroll
        for (int nt = 0; nt < 6; ++nt)
          oacc[mt][nt] = __builtin_amdgcn_mfma_f32_16x16x32_bf16(ha[mt], wb[nt], oacc[mt][nt], 0, 0, 0);
    }
    __syncthreads();   // B: fc2 reads done; next chunk may overwrite Hl/buf
  }

  // epilogue: out = h + oacc + b2
  #pragma unroll
  for (int mt = 0; mt < 2; ++mt) {
    #pragma unroll
    for (int nt = 0; nt < 6; ++nt) {
      int col = wn * 96 + nt * 16 + r;
      float b2v = b2[col];
      #pragma unroll
      for (int rr = 0; rr < 4; ++rr) {
        long row = m0 + wm * 32 + mt * 16 + kb * 4 + rr;
        outp[row * 192 + col] = h[row * 192 + col] + oacc[mt][nt][rr] + b2v;
      }
    }
  }
}

// Attention: one wave per (window, head). 49 tokens padded to 64.
__global__ __launch_bounds__(64) void attn_k(
    const bf16* __restrict__ qkv, const float* __restrict__ rpb,
    bf16* __restrict__ aout)
{
  __shared__ bf16 P[64 * 72];
  __shared__ bf16 Vt[32 * 72];
  int lane = threadIdx.x;
  int r = lane & 15, kb = lane >> 4;
  int head = blockIdx.x % 6;
  int win = blockIdx.x / 6;
  int iw = win & 63;
  int wh = iw >> 3, ww = iw & 7;
  const bf16* base = qkv + (long)win * (49 * 576);

  bf16x8 qf[4], kf[4];
  #pragma unroll
  for (int t = 0; t < 4; ++t) {
    int row = t * 16 + r;
    if (row < 49) {
      qf[t] = *(const bf16x8*)(base + row * 576 + head * 32 + kb * 8);
      kf[t] = *(const bf16x8*)(base + row * 576 + 192 + head * 32 + kb * 8);
    } else {
      qf[t] = (bf16x8){0, 0, 0, 0, 0, 0, 0, 0};
      kf[t] = (bf16x8){0, 0, 0, 0, 0, 0, 0, 0};
    }
  }
  f32x4 zero = {0.f, 0.f, 0.f, 0.f};
  f32x4 s[4][4];
  #pragma unroll
  for (int ti = 0; ti < 4; ++ti)
    #pragma unroll
    for (int tj = 0; tj < 4; ++tj)
      s[ti][tj] = __builtin_amdgcn_mfma_f32_16x16x32_bf16(qf[ti], kf[tj], zero, 0, 0, 0);

  {
    int j = lane;
    if (j < 49) {
      #pragma unroll
      for (int d0 = 0; d0 < 32; d0 += 8) {
        bf16x8 v8 = *(const bf16x8*)(base + j * 576 + 384 + head * 32 + d0);
        #pragma unroll
        for (int u = 0; u < 8; ++u) Vt[(d0 + u) * 72 + j] = *((const bf16*)&v8 + u);
      }
    } else {
      for (int d = 0; d < 32; ++d) Vt[d * 72 + j] = __float2bfloat16(0.0f);
    }
  }

  #pragma unroll
  for (int ti = 0; ti < 4; ++ti) {
    #pragma unroll
    for (int rr = 0; rr < 4; ++rr) {
      int i = ti * 16 + kb * 4 + rr;
      int ii = i < 49 ? i : 48;
      int yi = ii / 7, xi = ii - yi * 7;
      int ari = wh * 7 + yi, aci = ww * 7 + xi;
      int gi = (ari < 49 ? 0 : (ari < 53 ? 1 : 2)) * 3 + (aci < 49 ? 0 : (aci < 53 ? 1 : 2));
      float vals[4];
      #pragma unroll
      for (int tj = 0; tj < 4; ++tj) {
        int j = tj * 16 + r;
        int jj = j < 49 ? j : 48;
        int yj = jj / 7, xj = jj - yj * 7;
        float pb = rpb[((yi - yj + 6) * 13 + (xi - xj + 6)) * 6 + head];
        int arj = wh * 7 + yj, acj = ww * 7 + xj;
        int gj = (arj < 49 ? 0 : (arj < 53 ? 1 : 2)) * 3 + (acj < 49 ? 0 : (acj < 53 ? 1 : 2));
        float v = s[ti][tj][rr] * SCALE + pb;
        if (gi != gj) v -= 100.0f;
        if (i >= 49 || j >= 49) v = -1e30f;
        vals[tj] = v;
      }
      float mx = fmaxf(fmaxf(vals[0], vals[1]), fmaxf(vals[2], vals[3]));
      #pragma unroll
      for (int d = 1; d < 16; d <<= 1) mx = fmaxf(mx, __shfl_xor(mx, d, 64));
      float e0 = __expf(vals[0] - mx), e1 = __expf(vals[1] - mx);
      float e2 = __expf(vals[2] - mx), e3 = __expf(vals[3] - mx);
      float sum = e0 + e1 + e2 + e3;
      #pragma unroll
      for (int d = 1; d < 16; d <<= 1) sum += __shfl_xor(sum, d, 64);
      float inv = 1.0f / sum;
      P[i * 72 + 0  + r] = __float2bfloat16(e0 * inv);
      P[i * 72 + 16 + r] = __float2bfloat16(e1 * inv);
      P[i * 72 + 32 + r] = __float2bfloat16(e2 * inv);
      P[i * 72 + 48 + r] = __float2bfloat16(e3 * inv);
    }
  }
  __syncthreads();

  f32x4 o[4][2];
  #pragma unroll
  for (int ti = 0; ti < 4; ++ti)
    #pragma unroll
    for (int dt = 0; dt < 2; ++dt) o[ti][dt] = zero;
  #pragma unroll
  for (int kt = 0; kt < 2; ++kt) {
    bf16x8 pf[4], vf[2];
    #pragma unroll
    for (int ti = 0; ti < 4; ++ti)
      pf[ti] = *(const bf16x8*)(P + (ti * 16 + r) * 72 + kt * 32 + kb * 8);
    #pragma unroll
    for (int dt = 0; dt < 2; ++dt)
      vf[dt] = *(const bf16x8*)(Vt + (dt * 16 + r) * 72 + kt * 32 + kb * 8);
    #pragma unroll
    for (int ti = 0; ti < 4; ++ti)
      #pragma unroll
      for (int dt = 0; dt < 2; ++dt)
        o[ti][dt] = __builtin_amdgcn_mfma_f32_16x16x32_bf16(pf[ti], vf[dt], o[ti][dt], 0, 0, 0);
  }
  #pragma unroll
  for (int ti = 0; ti < 4; ++ti)
    #pragma unroll
    for (int dt = 0; dt < 2; ++dt)
      #pragma unroll
      for (int rr = 0; rr < 4; ++rr) {
        int i = ti * 16 + kb * 4 + rr;
        if (i < 49)
          aout[((long)win * 49 + i) * 192 + head * 32 + dt * 16 + r] =
              __float2bfloat16(o[ti][dt][rr]);
      }
}

extern "C" void kernel_launch(void* const* d_in, const int* in_sizes, int n_in,
                              void* d_out, int out_size, void* d_ws, size_t ws_size,
                              hipStream_t stream)
{
  const float* x      = (const float*)d_in[0];
  const float* qkv_w  = (const float*)d_in[1];
  const float* qkv_b  = (const float*)d_in[2];
  const float* proj_w = (const float*)d_in[3];
  const float* proj_b = (const float*)d_in[4];
  const float* rpb    = (const float*)d_in[5];
  const float* ln1_g  = (const float*)d_in[6];
  const float* ln1_b  = (const float*)d_in[7];
  const float* ln2_g  = (const float*)d_in[8];
  const float* ln2_b  = (const float*)d_in[9];
  const float* w1     = (const float*)d_in[10];
  const float* b1     = (const float*)d_in[11];
  const float* w2     = (const float*)d_in[12];
  const float* b2     = (const float*)d_in[13];

  char* ws = (char*)d_ws;
  bf16* wtq = (bf16*)(ws + OFF_WTQ);
  bf16* wtp = (bf16*)(ws + OFF_WTP);
  bf16* wt1 = (bf16*)(ws + OFF_WT1);
  bf16* wt2 = (bf16*)(ws + OFF_WT2);
  int*  rmap = (int*)(ws + OFF_RMAP);
  bf16* Abuf = (bf16*)(ws + OFF_A);
  bf16* Bbuf = (bf16*)(ws + OFF_B);
  float* hbuf = (float*)(ws + OFF_C);

  prep_k<<<2120, 256, 0, stream>>>(qkv_w, proj_w, w1, w2, wtq, wtp, wt1, wt2, rmap);
  ln_k<true><<<25088, 256, 0, stream>>>(x, ln1_g, ln1_b, rmap, Abuf);
  gemm_k<0, 192><<<dim3(9, 784), 256, 0, stream>>>(Abuf, wtq, qkv_b, nullptr, nullptr, Bbuf);
  attn_k<<<12288, 64, 0, stream>>>(Bbuf, rpb, Abuf);
  gemm_k<1, 192><<<dim3(3, 784), 256, 0, stream>>>(Abuf, wtp, proj_b, x, rmap, hbuf);
  mlp_k<<<1568, 256, 0, stream>>>(hbuf, ln2_g, ln2_b, wt1, b1, wt2, b2, (float*)d_out);
}